// Round 1
// baseline (398.619 us; speedup 1.0000x reference)
//
#include <hip/hip_runtime.h>
#include <hip/hip_bf16.h>
#include <math.h>

// DisRNNCellNet: time-distanced LSTM over 32 steps, 32768 independent rows,
// DIM=HID=64, then noisy-OR pooling over 8 nodules -> casePred[4096].
//
// Design: 512 blocks x 256 threads (4 waves). Block owns 64 rows for all 32
// steps (no inter-block deps). Weights held as MFMA B-fragments in VGPRs
// (wave w owns hidden cols [16w,16w+16) of all 4 gate quarters). X_s staged
// to LDS bf16 each step (XOR-chunk swizzle vs 16-way bank conflict); H kept
// in LDS bf16 between steps. mfma_f32_16x16x32_bf16, acc initialized to bias.

#define STEPS 32
#define BSIZE 4096
#define NNOD  8
#define DIMK  64
#define HIDK  64
#define BN    (BSIZE * NNOD)   // 32768
#define ROWS  64               // rows per block
#define NBLK  (BN / ROWS)      // 512

typedef __attribute__((ext_vector_type(8))) short short8;
typedef __attribute__((ext_vector_type(4))) float f32x4;

__device__ __forceinline__ unsigned short f2bf(float f) {
    union { float f; unsigned u; } v; v.f = f;
    unsigned r = v.u + 0x7fffu + ((v.u >> 16) & 1u);
    return (unsigned short)(r >> 16);
}
__device__ __forceinline__ float bf2f(unsigned short h) {
    union { unsigned u; float f; } v; v.u = ((unsigned)h) << 16;
    return v.f;
}
__device__ __forceinline__ float fast_sigmoid(float x) {
    float e = __builtin_amdgcn_exp2f(-1.44269504f * x);
    return __builtin_amdgcn_rcpf(1.0f + e);
}
__device__ __forceinline__ float fast_tanh(float x) {
    float e = __builtin_amdgcn_exp2f(2.88539008f * x);
    return 1.0f - 2.0f * __builtin_amdgcn_rcpf(e + 1.0f);
}

__global__ __launch_bounds__(256, 2)
void disrnn_kernel(const float* __restrict__ x,        // [S][BN][D]
                   const float* __restrict__ time_dis, // [B][S]
                   const float* __restrict__ w_ih,     // [4H][D]
                   const float* __restrict__ w_hh,     // [4H][H]
                   const float* __restrict__ b_ih,     // [4H]
                   const float* __restrict__ b_hh,     // [4H]
                   const float* __restrict__ fc2_w,    // [H]
                   const float* __restrict__ fc2_b,    // [1]
                   const float* __restrict__ baseline, // [1]
                   float* __restrict__ out)            // [B]
{
    __shared__ unsigned short sX[ROWS * 64];  // bf16, swizzled 8-elem chunks
    __shared__ unsigned short sH[ROWS * 64];  // bf16, swizzled 8-elem chunks
    __shared__ float sDecay[8 * STEPS];

    const int tid  = threadIdx.x;
    const int wave = tid >> 6;
    const int lane = tid & 63;
    const int l15  = lane & 15;   // N-col within 16-tile (also A-row)
    const int lk   = lane >> 4;   // k-chunk within MFMA k-step (0..3)
    const int blk  = blockIdx.x;
    const int row0 = blk * ROWS;

    // decay[g][s] = 1/log(e + time_dis[b][s==0?0:s-1]); b = blk*8+g
    {
        int g = tid >> 5, st = tid & 31;
        int b = blk * 8 + g;
        float td = time_dis[b * STEPS + (st == 0 ? 0 : st - 1)];
        sDecay[g * STEPS + st] = __builtin_amdgcn_rcpf(logf(2.71828182845904523f + td));
    }
    // h0 = 0
    for (int i = tid; i < ROWS * 64; i += 256) sH[i] = 0;

    // Weight B-fragments in VGPRs. Wave w covers gate rows n = q*64 + w*16 + l15.
    // B-frag: lane holds W[n][k0..k0+7] (8 contiguous k), n = l15 within tile.
    short8 bwih[4][2], bwhh[4][2];
    float  biasv[4];
    #pragma unroll
    for (int q = 0; q < 4; ++q) {
        int n = q * 64 + wave * 16 + l15;
        biasv[q] = b_ih[n] + b_hh[n];
        #pragma unroll
        for (int kk = 0; kk < 2; ++kk) {
            int k0 = kk * 32 + lk * 8;
            short8 vi, vh;
            #pragma unroll
            for (int j = 0; j < 8; ++j) {
                vi[j] = (short)f2bf(w_ih[n * 64 + k0 + j]);
                vh[j] = (short)f2bf(w_hh[n * 64 + k0 + j]);
            }
            bwih[q][kk] = vi;
            bwhh[q][kk] = vh;
        }
    }

    float c[4][4];
    #pragma unroll
    for (int m = 0; m < 4; ++m)
        #pragma unroll
        for (int j = 0; j < 4; ++j) c[m][j] = 0.0f;

    __syncthreads();  // sH zeros + sDecay visible

    for (int s = 0; s < STEPS; ++s) {
        // ---- stage X_s tile -> sX (bf16, swizzled). 512 chunks of 8, 2/thread.
        const float* Xs = x + ((size_t)s * BN + row0) * DIMK;
        #pragma unroll
        for (int it = 0; it < 2; ++it) {
            int gg = it * 256 + tid;        // chunk id 0..511
            int r  = gg >> 3, ch = gg & 7;
            const float4* src = (const float4*)(Xs + r * 64 + ch * 8);
            float4 a = src[0], b2 = src[1];
            short8 v;
            v[0] = (short)f2bf(a.x);  v[1] = (short)f2bf(a.y);
            v[2] = (short)f2bf(a.z);  v[3] = (short)f2bf(a.w);
            v[4] = (short)f2bf(b2.x); v[5] = (short)f2bf(b2.y);
            v[6] = (short)f2bf(b2.z); v[7] = (short)f2bf(b2.w);
            *(short8*)&sX[r * 64 + ((ch ^ (r & 7)) * 8)] = v;
        }
        __syncthreads();  // sX ready; prev-step sH writes visible

        // ---- gates = X@Wih^T + H@Whh^T + bias, via 16x16x32 bf16 MFMA
        f32x4 acc[4][4];
        #pragma unroll
        for (int m = 0; m < 4; ++m) {
            int rl = m * 16 + l15;
            int sw = rl & 7;
            short8 ax0 = *(const short8*)&sX[rl * 64 + (((0 + lk) ^ sw) * 8)];
            short8 ax1 = *(const short8*)&sX[rl * 64 + (((4 + lk) ^ sw) * 8)];
            short8 ah0 = *(const short8*)&sH[rl * 64 + (((0 + lk) ^ sw) * 8)];
            short8 ah1 = *(const short8*)&sH[rl * 64 + (((4 + lk) ^ sw) * 8)];
            #pragma unroll
            for (int q = 0; q < 4; ++q) {
                f32x4 a0 = {biasv[q], biasv[q], biasv[q], biasv[q]};
                a0 = __builtin_amdgcn_mfma_f32_16x16x32_bf16(ax0, bwih[q][0], a0, 0, 0, 0);
                a0 = __builtin_amdgcn_mfma_f32_16x16x32_bf16(ax1, bwih[q][1], a0, 0, 0, 0);
                a0 = __builtin_amdgcn_mfma_f32_16x16x32_bf16(ah0, bwhh[q][0], a0, 0, 0, 0);
                a0 = __builtin_amdgcn_mfma_f32_16x16x32_bf16(ah1, bwhh[q][1], a0, 0, 0, 0);
                acc[m][q] = a0;
            }
        }
        __syncthreads();  // all sH reads complete before h update

        // ---- elementwise LSTM update. C/D layout: col = l15, row = lk*4 + j.
        #pragma unroll
        for (int m = 0; m < 4; ++m) {
            #pragma unroll
            for (int j = 0; j < 4; ++j) {
                int rl = m * 16 + lk * 4 + j;
                float decay = sDecay[(rl >> 3) * STEPS + s];
                float ig = fast_sigmoid(acc[m][0][j]);
                float fg = fast_sigmoid(acc[m][1][j]);
                float g2 = fast_tanh(acc[m][2][j]);
                float og = fast_sigmoid(acc[m][3][j]);
                float cn = fg * decay * c[m][j] + ig * g2;
                c[m][j] = cn;
                float hn = og * fast_tanh(cn);
                int col = wave * 16 + l15;
                sH[rl * 64 + (((col >> 3) ^ (rl & 7)) * 8) + (col & 7)] = f2bf(hn);
            }
        }
        // next iteration's sX stage + barrier publishes these sH writes
    }
    __syncthreads();

    // ---- epilogue: out2 = sigmoid(h @ fc2_w + b); noisy-OR over 8 rows
    if (tid < 64) {
        int r = tid;
        float sum = 0.0f;
        #pragma unroll
        for (int ch = 0; ch < 8; ++ch) {
            short8 v = *(const short8*)&sH[r * 64 + ((ch ^ (r & 7)) * 8)];
            #pragma unroll
            for (int j = 0; j < 8; ++j)
                sum += bf2f((unsigned short)v[j]) * fc2_w[ch * 8 + j];
        }
        float p  = fast_sigmoid(sum + fc2_b[0]);
        float qv = 1.0f - p;
        qv *= __shfl_xor(qv, 1);
        qv *= __shfl_xor(qv, 2);
        qv *= __shfl_xor(qv, 4);
        if ((tid & 7) == 0) {
            float bp = fast_sigmoid(baseline[0]);
            out[blk * 8 + (tid >> 3)] = 1.0f - qv * (1.0f - bp);
        }
    }
}

extern "C" void kernel_launch(void* const* d_in, const int* in_sizes, int n_in,
                              void* d_out, int out_size, void* d_ws, size_t ws_size,
                              hipStream_t stream) {
    const float* x        = (const float*)d_in[0];
    const float* time_dis = (const float*)d_in[1];
    const float* w_ih     = (const float*)d_in[2];
    const float* w_hh     = (const float*)d_in[3];
    const float* b_ih     = (const float*)d_in[4];
    const float* b_hh     = (const float*)d_in[5];
    const float* fc2_w    = (const float*)d_in[6];
    const float* fc2_b    = (const float*)d_in[7];
    const float* baseline = (const float*)d_in[8];
    float* out = (float*)d_out;

    disrnn_kernel<<<dim3(NBLK), dim3(256), 0, stream>>>(
        x, time_dis, w_ih, w_hh, b_ih, b_hh, fc2_w, fc2_b, baseline, out);
}

// Round 3
// 383.209 us; speedup vs baseline: 1.0402x; 1.0402x over previous
//
#include <hip/hip_runtime.h>
#include <hip/hip_bf16.h>
#include <math.h>

// DisRNNCellNet: time-distanced LSTM over 32 steps, 32768 independent rows,
// DIM=HID=64, then noisy-OR pooling over 8 nodules -> casePred[4096].
//
// R2 (resubmit after broker timeout): software-pipelined X staging (prefetch
// X_{s+1} into VGPRs during step s) + raw s_barrier with lgkmcnt-only waits
// so prefetch loads stay in flight across barriers (hipcc's __syncthreads
// drains vmcnt(0) -> exposed HBM latency every step). Math/layout identical
// to the R1 passing version.

#define STEPS 32
#define BSIZE 4096
#define NNOD  8
#define DIMK  64
#define HIDK  64
#define BN    (BSIZE * NNOD)   // 32768
#define ROWS  64               // rows per block
#define NBLK  (BN / ROWS)      // 512

typedef __attribute__((ext_vector_type(8))) short short8;
typedef __attribute__((ext_vector_type(4))) float f32x4;

__device__ __forceinline__ unsigned short f2bf(float f) {
    union { float f; unsigned u; } v; v.f = f;
    unsigned r = v.u + 0x7fffu + ((v.u >> 16) & 1u);
    return (unsigned short)(r >> 16);
}
__device__ __forceinline__ float bf2f(unsigned short h) {
    union { unsigned u; float f; } v; v.u = ((unsigned)h) << 16;
    return v.f;
}
__device__ __forceinline__ float fast_sigmoid(float x) {
    float e = __builtin_amdgcn_exp2f(-1.44269504f * x);
    return __builtin_amdgcn_rcpf(1.0f + e);
}
__device__ __forceinline__ float fast_tanh(float x) {
    float e = __builtin_amdgcn_exp2f(2.88539008f * x);
    return 1.0f - 2.0f * __builtin_amdgcn_rcpf(e + 1.0f);
}
// Barrier that drains LDS ops only — in-flight global loads (prefetch)
// survive. asm "memory" fences pin compiler memory-op ordering around it.
__device__ __forceinline__ void block_sync_lds() {
    asm volatile("s_waitcnt lgkmcnt(0)" ::: "memory");
    __builtin_amdgcn_s_barrier();
    asm volatile("" ::: "memory");
}

__global__ __launch_bounds__(256, 2)
void disrnn_kernel(const float* __restrict__ x,        // [S][BN][D]
                   const float* __restrict__ time_dis, // [B][S]
                   const float* __restrict__ w_ih,     // [4H][D]
                   const float* __restrict__ w_hh,     // [4H][H]
                   const float* __restrict__ b_ih,     // [4H]
                   const float* __restrict__ b_hh,     // [4H]
                   const float* __restrict__ fc2_w,    // [H]
                   const float* __restrict__ fc2_b,    // [1]
                   const float* __restrict__ baseline, // [1]
                   float* __restrict__ out)            // [B]
{
    __shared__ unsigned short sX[ROWS * 64];  // bf16, swizzled 8-elem chunks
    __shared__ unsigned short sH[ROWS * 64];  // bf16, swizzled 8-elem chunks
    __shared__ float sDecay[8 * STEPS];

    const int tid  = threadIdx.x;
    const int wave = tid >> 6;
    const int lane = tid & 63;
    const int l15  = lane & 15;   // N-col within 16-tile (also A-row)
    const int lk   = lane >> 4;   // k-chunk within MFMA k-step (0..3)
    const int blk  = blockIdx.x;
    const int row0 = blk * ROWS;

    // Per-thread staging coordinates (2 chunks of 8 elems per thread)
    const int r0 = tid >> 3,        c0 = tid & 7;
    const int r1 = (256 + tid) >> 3, c1 = tid & 7;  // (256+tid)&7 == tid&7

    // ---- issue X_0 prefetch FIRST (latency hides under setup below)
    float4 pa0, pa1, pb0, pb1;
    {
        const float* Xs = x + (size_t)row0 * DIMK;
        const float* s0 = Xs + r0 * 64 + c0 * 8;
        const float* s1 = Xs + r1 * 64 + c1 * 8;
        pa0 = ((const float4*)s0)[0]; pa1 = ((const float4*)s0)[1];
        pb0 = ((const float4*)s1)[0]; pb1 = ((const float4*)s1)[1];
    }

    // decay[g][s] = 1/log(e + time_dis[b][s==0?0:s-1]); b = blk*8+g
    {
        int g = tid >> 5, st = tid & 31;
        int b = blk * 8 + g;
        float td = time_dis[b * STEPS + (st == 0 ? 0 : st - 1)];
        sDecay[g * STEPS + st] = __builtin_amdgcn_rcpf(logf(2.71828182845904523f + td));
    }
    // h0 = 0
    for (int i = tid; i < ROWS * 64; i += 256) sH[i] = 0;

    // Weight B-fragments in VGPRs. Wave w covers gate rows n = q*64 + w*16 + l15.
    short8 bwih[4][2], bwhh[4][2];
    float  biasv[4];
    #pragma unroll
    for (int q = 0; q < 4; ++q) {
        int n = q * 64 + wave * 16 + l15;
        biasv[q] = b_ih[n] + b_hh[n];
        #pragma unroll
        for (int kk = 0; kk < 2; ++kk) {
            int k0 = kk * 32 + lk * 8;
            short8 vi, vh;
            #pragma unroll
            for (int j = 0; j < 8; ++j) {
                vi[j] = (short)f2bf(w_ih[n * 64 + k0 + j]);
                vh[j] = (short)f2bf(w_hh[n * 64 + k0 + j]);
            }
            bwih[q][kk] = vi;
            bwhh[q][kk] = vh;
        }
    }

    float c[4][4];
    #pragma unroll
    for (int m = 0; m < 4; ++m)
        #pragma unroll
        for (int j = 0; j < 4; ++j) c[m][j] = 0.0f;

    block_sync_lds();  // sH zeros + sDecay visible (X_0 loads stay in flight)

    for (int s = 0; s < STEPS; ++s) {
        // ---- Phase A: convert prefetched X_s regs -> sX (bf16, swizzled)
        {
            short8 v;
            v[0] = (short)f2bf(pa0.x); v[1] = (short)f2bf(pa0.y);
            v[2] = (short)f2bf(pa0.z); v[3] = (short)f2bf(pa0.w);
            v[4] = (short)f2bf(pa1.x); v[5] = (short)f2bf(pa1.y);
            v[6] = (short)f2bf(pa1.z); v[7] = (short)f2bf(pa1.w);
            *(short8*)&sX[r0 * 64 + ((c0 ^ (r0 & 7)) * 8)] = v;
            short8 w2;
            w2[0] = (short)f2bf(pb0.x); w2[1] = (short)f2bf(pb0.y);
            w2[2] = (short)f2bf(pb0.z); w2[3] = (short)f2bf(pb0.w);
            w2[4] = (short)f2bf(pb1.x); w2[5] = (short)f2bf(pb1.y);
            w2[6] = (short)f2bf(pb1.z); w2[7] = (short)f2bf(pb1.w);
            *(short8*)&sX[r1 * 64 + ((c1 ^ (r1 & 7)) * 8)] = w2;
        }
        // ---- issue prefetch for X_{s+1}; stays in flight across barriers
        if (s + 1 < STEPS) {
            const float* Xs = x + ((size_t)(s + 1) * BN + row0) * DIMK;
            const float* s0 = Xs + r0 * 64 + c0 * 8;
            const float* s1 = Xs + r1 * 64 + c1 * 8;
            pa0 = ((const float4*)s0)[0]; pa1 = ((const float4*)s0)[1];
            pb0 = ((const float4*)s1)[0]; pb1 = ((const float4*)s1)[1];
        }
        block_sync_lds();  // sX ready; prev-step sH writes visible

        // ---- Phase B: gates = X@Wih^T + H@Whh^T + bias (16x16x32 bf16 MFMA)
        f32x4 acc[4][4];
        #pragma unroll
        for (int m = 0; m < 4; ++m) {
            int rl = m * 16 + l15;
            int sw = rl & 7;
            short8 ax0 = *(const short8*)&sX[rl * 64 + (((0 + lk) ^ sw) * 8)];
            short8 ax1 = *(const short8*)&sX[rl * 64 + (((4 + lk) ^ sw) * 8)];
            short8 ah0 = *(const short8*)&sH[rl * 64 + (((0 + lk) ^ sw) * 8)];
            short8 ah1 = *(const short8*)&sH[rl * 64 + (((4 + lk) ^ sw) * 8)];
            #pragma unroll
            for (int q = 0; q < 4; ++q) {
                f32x4 a0 = {biasv[q], biasv[q], biasv[q], biasv[q]};
                a0 = __builtin_amdgcn_mfma_f32_16x16x32_bf16(ax0, bwih[q][0], a0, 0, 0, 0);
                a0 = __builtin_amdgcn_mfma_f32_16x16x32_bf16(ax1, bwih[q][1], a0, 0, 0, 0);
                a0 = __builtin_amdgcn_mfma_f32_16x16x32_bf16(ah0, bwhh[q][0], a0, 0, 0, 0);
                a0 = __builtin_amdgcn_mfma_f32_16x16x32_bf16(ah1, bwhh[q][1], a0, 0, 0, 0);
                acc[m][q] = a0;
            }
        }
        block_sync_lds();  // all sH reads complete before h update

        // ---- Phase C: elementwise LSTM update. C/D: col = l15, row = lk*4+j.
        #pragma unroll
        for (int m = 0; m < 4; ++m) {
            const float decay = sDecay[(m * 2 + (lk >> 1)) * STEPS + s];
            #pragma unroll
            for (int j = 0; j < 4; ++j) {
                int rl = m * 16 + lk * 4 + j;
                float ig = fast_sigmoid(acc[m][0][j]);
                float fg = fast_sigmoid(acc[m][1][j]);
                float g2 = fast_tanh(acc[m][2][j]);
                float og = fast_sigmoid(acc[m][3][j]);
                float cn = fg * decay * c[m][j] + ig * g2;
                c[m][j] = cn;
                float hn = og * fast_tanh(cn);
                int col = wave * 16 + l15;
                sH[rl * 64 + (((col >> 3) ^ (rl & 7)) * 8) + (col & 7)] = f2bf(hn);
            }
        }
        // sH writes drained by next iteration's (or epilogue's) block_sync_lds
    }
    block_sync_lds();

    // ---- epilogue: out2 = sigmoid(h @ fc2_w + b); noisy-OR over 8 rows
    if (tid < 64) {
        int r = tid;
        float sum = 0.0f;
        #pragma unroll
        for (int ch = 0; ch < 8; ++ch) {
            short8 v = *(const short8*)&sH[r * 64 + ((ch ^ (r & 7)) * 8)];
            #pragma unroll
            for (int j = 0; j < 8; ++j)
                sum += bf2f((unsigned short)v[j]) * fc2_w[ch * 8 + j];
        }
        float p  = fast_sigmoid(sum + fc2_b[0]);
        float qv = 1.0f - p;
        qv *= __shfl_xor(qv, 1);
        qv *= __shfl_xor(qv, 2);
        qv *= __shfl_xor(qv, 4);
        if ((tid & 7) == 0) {
            float bp = fast_sigmoid(baseline[0]);
            out[blk * 8 + (tid >> 3)] = 1.0f - qv * (1.0f - bp);
        }
    }
}

extern "C" void kernel_launch(void* const* d_in, const int* in_sizes, int n_in,
                              void* d_out, int out_size, void* d_ws, size_t ws_size,
                              hipStream_t stream) {
    const float* x        = (const float*)d_in[0];
    const float* time_dis = (const float*)d_in[1];
    const float* w_ih     = (const float*)d_in[2];
    const float* w_hh     = (const float*)d_in[3];
    const float* b_ih     = (const float*)d_in[4];
    const float* b_hh     = (const float*)d_in[5];
    const float* fc2_w    = (const float*)d_in[6];
    const float* fc2_b    = (const float*)d_in[7];
    const float* baseline = (const float*)d_in[8];
    float* out = (float*)d_out;

    disrnn_kernel<<<dim3(NBLK), dim3(256), 0, stream>>>(
        x, time_dis, w_ih, w_hh, b_ih, b_hh, fc2_w, fc2_b, baseline, out);
}